// Round 1
// baseline (414.216 us; speedup 1.0000x reference)
//
#include <hip/hip_runtime.h>
#include <hip/hip_fp16.h>
#include <cstdint>

// Problem constants (fixed by the reference)
#define NROWS 65536
#define DIM   512    // D
#define KDIM  256    // K
#define ODIM  512    // O
#define DEG   8
#define TN    (DEG * KDIM * DIM)   // 1048576 T elements
#define CWN   (ODIM * KDIM)        // 131072 C_w elements

typedef _Float16 f16x8 __attribute__((ext_vector_type(8)));
typedef float    f32x4 __attribute__((ext_vector_type(4)));

// ---- helpers -------------------------------------------------------------

// async 16B global->LDS (global_load_lds_dwordx4). LDS dest is wave-uniform
// base + lane*16 by HW rule; slot mappings honor that.
__device__ __forceinline__ void gld_lds16(const void* g, void* l) {
  __builtin_amdgcn_global_load_lds(
      (const __attribute__((address_space(1))) unsigned int*)g,
      (__attribute__((address_space(3))) unsigned int*)l, 16, 0, 0);
}

__device__ __forceinline__ unsigned pack2h(float a, float b) {
  union { _Float16 h[2]; unsigned u; } x;
  x.h[0] = (_Float16)a; x.h[1] = (_Float16)b;   // RNE, same as old k_convert
  return x.u;
}

// Swizzled byte offset in a tile of 64-half rows (128B = 8 x 16B chunks).
// chunk c of row r lives at slot (c+r)&7 -> conflict-free ds_read_b128.
__device__ __forceinline__ int swz(int row, int chunk) {
  return (row << 7) | (((chunk + row) & 7) << 4);
}

// ---- kernel 0: fp32->fp16 conversion, T (a_n folded) + C_w only ----------
// z conversion is now fused into k_poly's A-staging.

__global__ void k_convert(const float* __restrict__ T,
                          const float* __restrict__ Cw,
                          _Float16* __restrict__ Tb,
                          _Float16* __restrict__ Cwb) {
  long e = ((long)blockIdx.x * 256 + threadIdx.x) * 4;
  const float* src;
  _Float16* dst;
  float s = 1.0f;
  if (e < TN) {
    int n = (int)(e >> 17);  // / (KDIM*DIM); Tb[n] holds degree n+1
    s = (n == 0) ? 1.0f : (float)(2 * n + 1) / (float)(n + 1);
    src = T + e; dst = Tb + e;
  } else {
    long c = e - TN;
    if (c >= CWN) return;
    src = Cw + c; dst = Cwb + c;
  }
  float4 v = *(const float4*)src;
  uint2 p; p.x = pack2h(v.x * s, v.y * s); p.y = pack2h(v.z * s, v.w * s);
  *(uint2*)dst = p;
}

// ---- kernel 1: fused convert+GEMM+recurrence -----------------------------
// Block tile: 128 rows x 16 u-cols x 8 degrees, K-step 64.
// A path: z fp32 -> regs -> cvt fp16 -> swizzled ds_write (fused conversion).
// B path: pre-converted Tb via async global_load_lds, double-buffered.
// 2-phase pipeline with raw s_barrier + manual waitcnt so next-tile loads
// stay in flight across the barrier (avoid __syncthreads vmcnt(0) drain).
// XCD-chunked swizzle: all 16 kg blocks of a row tile on one XCD -> z fp32
// re-reads are L2 hits; each z byte fetched from HBM once.

__launch_bounds__(256, 3)
__global__ void k_poly(const float* __restrict__ z,
                       const float* __restrict__ T0,
                       const _Float16* __restrict__ Tb,
                       _Float16* __restrict__ u8) {
  __shared__ __align__(16) uint16_t As[128 * 64];      // 16 KB z tile (fp16)
  __shared__ __align__(16) uint16_t Bs[2][128 * 64];   // 2 x 16 KB Tb tile

  const int tid = threadIdx.x;
  const int wave = tid >> 6, lane = tid & 63;

  // XCD-chunked mapping: xcd = id&7 owns row tiles [xcd*64, xcd*64+64),
  // consecutive s within an xcd walk kg fastest -> same-rt blocks co-resident.
  const int id = blockIdx.x;
  const int xcd = id & 7;
  const int s = id >> 3;                     // 0..1023
  const int kg = s & 15;                     // 0..15 (16 u-cols each)
  const int rt = (xcd << 6) | (s >> 4);      // 0..511 row tile
  const int r0 = rt << 7;
  const int k0 = kg << 4;

  const int m_l = lane & 15, kq = lane >> 4;
  const int wrow = wave << 5;                // 32 rows per wave

  f32x4 acc[DEG][2];
#pragma unroll
  for (int n = 0; n < DEG; n++)
#pragma unroll
    for (int a = 0; a < 2; a++)
      acc[n][a] = (f32x4){0.f, 0.f, 0.f, 0.f};

  // B staging addresses (async gld_lds, linear dest + pre-swizzled source).
  const _Float16* bptr[4];
  int lofsB[4];
#pragma unroll
  for (int j = 0; j < 4; j++) {
    int lin = (j << 8) + tid;
    int row = lin >> 3;
    int c = ((lin & 7) - row) & 7;
    lofsB[j] = lin << 4;
    int n = row >> 4, kk = row & 15;
    bptr[j] = Tb + (size_t)((n << 8) + k0 + kk) * DIM + (c << 3);
  }

  // A staging: per thread 8 float4 (128B fp32) per K-step.
  // chunk q = j*256+tid -> row = j*16 + (tid>>4), c = tid&15 (4-float chunk).
  // Per-instr: wave = 4 rows x 256B contiguous -> fully coalesced.
  const int arow = tid >> 4;                 // 0..15
  const int ac = tid & 15;                   // 4-float chunk within 64
  const float* abase = z + (size_t)(r0 + arow) * DIM + (ac << 2);
  int aofs[8];
#pragma unroll
  for (int j = 0; j < 8; j++) {
    int row = (j << 4) + arow;
    // fp16 dest: 8B slot, consistent with swz() read layout (chunk = ac>>1)
    aofs[j] = (row << 7) | ((((ac >> 1) + row) & 7) << 4) | ((ac & 1) << 3);
  }

  // Prologue: issue tile-0 loads.
  float4 rA[8];
#pragma unroll
  for (int j = 0; j < 8; j++)
    rA[j] = *(const float4*)(abase + (size_t)(j << 4) * DIM);
#pragma unroll
  for (int j = 0; j < 4; j++) gld_lds16(bptr[j], (char*)Bs[0] + lofsB[j]);

  for (int it = 0; it < DIM / 64; it++) {
    const int cur = it & 1;
    // rA(it) regs + B(it) gld_lds landed; all waves done reading tile it-1.
    asm volatile("s_waitcnt vmcnt(0)" ::: "memory");
    __builtin_amdgcn_sched_barrier(0);
    __builtin_amdgcn_s_barrier();

    // convert + store A(it) to LDS (swizzled ds_write_b64)
#pragma unroll
    for (int j = 0; j < 8; j++) {
      uint2 p;
      p.x = pack2h(rA[j].x, rA[j].y);
      p.y = pack2h(rA[j].z, rA[j].w);
      *(uint2*)((char*)As + aofs[j]) = p;
    }

    // issue next-tile loads; they stay in flight across barrier2 + compute
    if (it < DIM / 64 - 1) {
#pragma unroll
      for (int j = 0; j < 8; j++)
        rA[j] = *(const float4*)(abase + ((it + 1) << 6) +
                                 (size_t)(j << 4) * DIM);
#pragma unroll
      for (int j = 0; j < 4; j++)
        gld_lds16(bptr[j] + ((it + 1) << 6), (char*)Bs[cur ^ 1] + lofsB[j]);
    }

    // only drain LDS writes (A visible); do NOT drain vmcnt here
    asm volatile("s_waitcnt lgkmcnt(0)" ::: "memory");
    __builtin_amdgcn_sched_barrier(0);
    __builtin_amdgcn_s_barrier();

    // compute tile it
#pragma unroll
    for (int ks = 0; ks < 2; ks++) {
      const int chunk = (ks << 2) + kq;
      f16x8 af[2];
#pragma unroll
      for (int mf = 0; mf < 2; mf++)
        af[mf] = *(const f16x8*)((char*)As + swz(wrow + (mf << 4) + m_l, chunk));
#pragma unroll
      for (int n = 0; n < DEG; n++) {
        f16x8 bv = *(const f16x8*)((char*)Bs[cur] + swz((n << 4) + m_l, chunk));
#pragma unroll
        for (int mf = 0; mf < 2; mf++)
          acc[n][mf] = __builtin_amdgcn_mfma_f32_16x16x32_f16(
              af[mf], bv, acc[n][mf], 0, 0, 0);
      }
    }
  }

  // Legendre recurrence per accumulator element, store u8 fp16.
  // C/D layout: col = lane&15, row = (lane>>4)*4 + reg  [m89-verified]
  const float bcoef[7] = {1.f/2.f, 2.f/3.f, 3.f/4.f, 4.f/5.f,
                          5.f/6.f, 6.f/7.f, 7.f/8.f};
  const int col = k0 + m_l;
  const float t0v = T0[col];
#pragma unroll
  for (int mf = 0; mf < 2; mf++) {
    f32x4 up2 = {t0v, t0v, t0v, t0v};
    f32x4 up1 = acc[0][mf];
#pragma unroll
    for (int n = 2; n <= DEG; n++) {
      f32x4 cur = acc[n - 1][mf] * up1 - bcoef[n - 2] * up2;
      up2 = up1; up1 = cur;
    }
    const int rbase = r0 + wrow + (mf << 4) + (kq << 2);
#pragma unroll
    for (int r = 0; r < 4; r++)
      u8[(size_t)(rbase + r) * KDIM + col] = (_Float16)up1[r];
  }
}

// ---- kernel 2: out[N,512] = u8[N,256] @ Cw^T + C_b (fp32 out) ------------
// Block tile 128 rows x 64 out-cols; 4 K-iterations of 64.
// XCD swizzle: 8 cg blocks of a row tile share u8 rows -> same XCD L2.

__launch_bounds__(256, 4)
__global__ void k_out(const _Float16* __restrict__ u8,
                      const _Float16* __restrict__ Cwb,
                      const float* __restrict__ Cb,
                      float* __restrict__ out) {
  __shared__ __align__(16) uint16_t As[128 * 64];  // 16 KB u8 tile
  __shared__ __align__(16) uint16_t Bs[64 * 64];   //  8 KB Cw tile

  const int tid = threadIdx.x;
  const int wave = tid >> 6, lane = tid & 63;

  const int id = blockIdx.x;
  const int xcd = id & 7;
  const int s = id >> 3;                     // 0..511
  const int cg = s & 7;                      // 0..7 out-col group (64)
  const int rt = (xcd << 6) | (s >> 3);      // 0..511 row tile
  const int r0 = rt << 7;
  const int c0 = cg << 6;

  const int m_l = lane & 15, kq = lane >> 4;
  const int wrow = wave << 5;

  f32x4 acc[2][4];
#pragma unroll
  for (int a = 0; a < 2; a++)
#pragma unroll
    for (int b = 0; b < 4; b++)
      acc[a][b] = (f32x4){0.f, 0.f, 0.f, 0.f};

  const _Float16* aptr[4];
  const _Float16* bptr[2];
  int lofsA[4], lofsB[2];
#pragma unroll
  for (int j = 0; j < 4; j++) {
    int lin = (j << 8) + tid;
    int row = lin >> 3;
    int c = ((lin & 7) - row) & 7;
    lofsA[j] = lin << 4;
    aptr[j] = u8 + (size_t)(r0 + row) * KDIM + (c << 3);
  }
#pragma unroll
  for (int j = 0; j < 2; j++) {
    int lin = (j << 8) + tid;
    int row = lin >> 3;
    int c = ((lin & 7) - row) & 7;
    lofsB[j] = lin << 4;
    bptr[j] = Cwb + (size_t)(c0 + row) * KDIM + (c << 3);
  }

  for (int it = 0; it < KDIM / 64; it++) {
    __syncthreads();
#pragma unroll
    for (int j = 0; j < 4; j++) gld_lds16(aptr[j], (char*)As + lofsA[j]);
#pragma unroll
    for (int j = 0; j < 2; j++) gld_lds16(bptr[j], (char*)Bs + lofsB[j]);
#pragma unroll
    for (int j = 0; j < 4; j++) aptr[j] += 64;
#pragma unroll
    for (int j = 0; j < 2; j++) bptr[j] += 64;
    __syncthreads();

#pragma unroll
    for (int ks = 0; ks < 2; ks++) {
      const int chunk = (ks << 2) + kq;
      f16x8 af[2];
#pragma unroll
      for (int mf = 0; mf < 2; mf++)
        af[mf] = *(const f16x8*)((char*)As + swz(wrow + (mf << 4) + m_l, chunk));
#pragma unroll
      for (int kf = 0; kf < 4; kf++) {
        f16x8 bv = *(const f16x8*)((char*)Bs + swz((kf << 4) + m_l, chunk));
#pragma unroll
        for (int mf = 0; mf < 2; mf++)
          acc[mf][kf] = __builtin_amdgcn_mfma_f32_16x16x32_f16(
              af[mf], bv, acc[mf][kf], 0, 0, 0);
      }
    }
  }

#pragma unroll
  for (int kf = 0; kf < 4; kf++) {
    const int col = c0 + (kf << 4) + m_l;
    const float cb = Cb[col];
#pragma unroll
    for (int mf = 0; mf < 2; mf++) {
      const int rbase = r0 + wrow + (mf << 4) + (kq << 2);
#pragma unroll
      for (int r = 0; r < 4; r++)
        out[(size_t)(rbase + r) * ODIM + col] = acc[mf][kf][r] + cb;
    }
  }
}

// ---- launch --------------------------------------------------------------

extern "C" void kernel_launch(void* const* d_in, const int* in_sizes, int n_in,
                              void* d_out, int out_size, void* d_ws, size_t ws_size,
                              hipStream_t stream) {
  const float* z  = (const float*)d_in[0];
  const float* T0 = (const float*)d_in[1];
  const float* T  = (const float*)d_in[2];
  const float* Cw = (const float*)d_in[3];
  const float* Cb = (const float*)d_in[4];
  float* out = (float*)d_out;

  // ws layout: Tb 2MB | Cwb 256KB | u8 32MB  (~34.25 MB; z16 eliminated)
  char* ws = (char*)d_ws;
  _Float16* Tb  = (_Float16*)ws;
  _Float16* Cwb = (_Float16*)(ws + (size_t)TN * 2);
  _Float16* u8  = (_Float16*)(ws + (size_t)TN * 2 + (size_t)CWN * 2);

  // (TN+CWN)/4 threads / 256 = 1152 blocks exactly
  k_convert<<<1152, 256, 0, stream>>>(T, Cw, Tb, Cwb);
  k_poly<<<8192, 256, 0, stream>>>(z, T0, Tb, u8);
  k_out<<<4096, 256, 0, stream>>>(u8, Cwb, Cb, out);
}

// Round 2
// 377.725 us; speedup vs baseline: 1.0966x; 1.0966x over previous
//
#include <hip/hip_runtime.h>
#include <hip/hip_fp16.h>
#include <cstdint>

// Problem constants (fixed by the reference)
#define NROWS 65536
#define DIM   512    // D
#define KDIM  256    // K
#define ODIM  512    // O
#define DEG   8
#define ZN    (NROWS * DIM)        // 33554432 z elements
#define TN    (DEG * KDIM * DIM)   // 1048576 T elements
#define CWN   (ODIM * KDIM)        // 131072 C_w elements

typedef _Float16 f16x8 __attribute__((ext_vector_type(8)));
typedef float    f32x4 __attribute__((ext_vector_type(4)));

// ---- helpers -------------------------------------------------------------

// async 16B global->LDS (global_load_lds_dwordx4). LDS dest is wave-uniform
// base + lane*16 by HW rule; all our slot mappings honor that.
__device__ __forceinline__ void gld_lds16(const void* g, void* l) {
  __builtin_amdgcn_global_load_lds(
      (const __attribute__((address_space(1))) unsigned int*)g,
      (__attribute__((address_space(3))) unsigned int*)l, 16, 0, 0);
}

__device__ __forceinline__ unsigned pack2h(float a, float b) {
  union { _Float16 h[2]; unsigned u; } x;
  x.h[0] = (_Float16)a; x.h[1] = (_Float16)b;
  return x.u;
}

// Swizzled byte offset in a tile of 64-half rows (128B = 8 x 16B chunks).
// chunk c of row r lives at slot (c+r)&7 -> conflict-free ds_read_b128.
__device__ __forceinline__ int swz(int row, int chunk) {
  return (row << 7) | (((chunk + row) & 7) << 4);
}

// ---- kernel 0: fp32->fp16 conversions (z, T with a_n folded, C_w) --------

__global__ void k_convert(const float* __restrict__ z,
                          const float* __restrict__ T,
                          const float* __restrict__ Cw,
                          _Float16* __restrict__ z16,
                          _Float16* __restrict__ Tb,
                          _Float16* __restrict__ Cwb) {
  long e = ((long)blockIdx.x * 256 + threadIdx.x) * 4;
  const float* src;
  _Float16* dst;
  float s = 1.0f;
  if (e < ZN) {
    src = z + e; dst = z16 + e;
  } else {
    long o = e - ZN;
    if (o < TN) {
      int n = (int)(o >> 17);  // / (KDIM*DIM); Tb[n] holds degree n+1
      s = (n == 0) ? 1.0f : (float)(2 * n + 1) / (float)(n + 1);
      src = T + o; dst = Tb + o;
    } else {
      long c = o - TN;
      if (c >= CWN) return;
      src = Cw + c; dst = Cwb + c;
    }
  }
  float4 v = *(const float4*)src;
  uint2 p; p.x = pack2h(v.x * s, v.y * s); p.y = pack2h(v.z * s, v.w * s);
  *(uint2*)dst = p;
}

// ---- kernel 1: fused GEMM [Nx512]x[512x(16x8deg)] + degree recurrence ----
// Round-0 proven structure (all staging via gld_lds from pre-converted z16)
// + counted-vmcnt B prefetch: Bs double-buffered, B(it+1) issued during
// iter it and left in flight (vmcnt(4)) across compute + barrier.
// Per-wave vmcnt ledger at the wait in iter it (it<7):
//   outstanding = B(it):4 + A(it):4 + B(it+1):4 -> vmcnt(4) drains A(it),B(it).

__launch_bounds__(256, 3)
__global__ void k_poly(const _Float16* __restrict__ z16,
                       const float* __restrict__ T0,
                       const _Float16* __restrict__ Tb,
                       _Float16* __restrict__ u8) {
  __shared__ __align__(16) uint16_t As[128 * 64];      // 16 KB z tile
  __shared__ __align__(16) uint16_t Bs[2][128 * 64];   // 2 x 16 KB Tb tile

  const int tid = threadIdx.x;
  const int wave = tid >> 6, lane = tid & 63;

  // super-tile: 16 row-tiles x 16 k-groups -> z16 slice (2MB) + Tb (2MB) ~ L2
  const int id = blockIdx.x;
  const int super = id >> 8, rem = id & 255;
  const int kg = rem >> 4;                    // 0..15 (16 u-cols each)
  const int rt = (super << 4) | (rem & 15);   // 0..511 row tile
  const int r0 = rt << 7;
  const int k0 = kg << 4;

  const int m_l = lane & 15, kq = lane >> 4;
  const int wrow = wave << 5;                 // 32 rows per wave

  f32x4 acc[DEG][2];
#pragma unroll
  for (int n = 0; n < DEG; n++)
#pragma unroll
    for (int a = 0; a < 2; a++)
      acc[n][a] = (f32x4){0.f, 0.f, 0.f, 0.f};

  // Hoisted staging addresses. Slot lin=j*256+tid, row=lin>>3,
  // c=((lin&7)-row)&7 inverts the swizzle on the global side.
  const _Float16* aptr[4];
  const _Float16* bptr[4];
  int lofs[4];
#pragma unroll
  for (int j = 0; j < 4; j++) {
    int lin = (j << 8) + tid;
    int row = lin >> 3;
    int c = ((lin & 7) - row) & 7;
    lofs[j] = lin << 4;
    aptr[j] = z16 + (size_t)(r0 + row) * DIM + (c << 3);
    int n = row >> 4, kk = row & 15;
    bptr[j] = Tb + (size_t)((n << 8) + k0 + kk) * DIM + (c << 3);
  }

  // Prologue: issue B(0).
#pragma unroll
  for (int j = 0; j < 4; j++) gld_lds16(bptr[j], (char*)Bs[0] + lofs[j]);
#pragma unroll
  for (int j = 0; j < 4; j++) bptr[j] += 64;

  for (int it = 0; it < DIM / 64; it++) {
    const int cur = it & 1;
    __builtin_amdgcn_sched_barrier(0);
    __builtin_amdgcn_s_barrier();   // As & Bs[cur^1] free (readers drained:
                                    // every ds_read was consumed by an MFMA)
    __builtin_amdgcn_sched_barrier(0);

#pragma unroll
    for (int j = 0; j < 4; j++) gld_lds16(aptr[j], (char*)As + lofs[j]);
#pragma unroll
    for (int j = 0; j < 4; j++) aptr[j] += 64;

    if (it < DIM / 64 - 1) {
#pragma unroll
      for (int j = 0; j < 4; j++)
        gld_lds16(bptr[j], (char*)Bs[cur ^ 1] + lofs[j]);
#pragma unroll
      for (int j = 0; j < 4; j++) bptr[j] += 64;
      asm volatile("s_waitcnt vmcnt(4)" ::: "memory");  // B(it+1) stays in flight
    } else {
      asm volatile("s_waitcnt vmcnt(0)" ::: "memory");
    }
    __builtin_amdgcn_sched_barrier(0);
    __builtin_amdgcn_s_barrier();   // all waves' A(it),B(it) landed
    __builtin_amdgcn_sched_barrier(0);

#pragma unroll
    for (int ks = 0; ks < 2; ks++) {
      const int chunk = (ks << 2) + kq;
      f16x8 af[2];
#pragma unroll
      for (int mf = 0; mf < 2; mf++)
        af[mf] = *(const f16x8*)((char*)As + swz(wrow + (mf << 4) + m_l, chunk));
#pragma unroll
      for (int n = 0; n < DEG; n++) {
        f16x8 bv = *(const f16x8*)((char*)Bs[cur] + swz((n << 4) + m_l, chunk));
#pragma unroll
        for (int mf = 0; mf < 2; mf++)
          acc[n][mf] = __builtin_amdgcn_mfma_f32_16x16x32_f16(
              af[mf], bv, acc[n][mf], 0, 0, 0);
      }
    }
  }

  // Legendre recurrence per accumulator element, store u8 fp16.
  // C/D layout: col = lane&15, row = (lane>>4)*4 + reg  [m89-verified]
  const float bcoef[7] = {1.f/2.f, 2.f/3.f, 3.f/4.f, 4.f/5.f,
                          5.f/6.f, 6.f/7.f, 7.f/8.f};
  const int col = k0 + m_l;
  const float t0v = T0[col];
#pragma unroll
  for (int mf = 0; mf < 2; mf++) {
    f32x4 up2 = {t0v, t0v, t0v, t0v};
    f32x4 up1 = acc[0][mf];
#pragma unroll
    for (int n = 2; n <= DEG; n++) {
      f32x4 cur = acc[n - 1][mf] * up1 - bcoef[n - 2] * up2;
      up2 = up1; up1 = cur;
    }
    const int rbase = r0 + wrow + (mf << 4) + (kq << 2);
#pragma unroll
    for (int r = 0; r < 4; r++)
      u8[(size_t)(rbase + r) * KDIM + col] = (_Float16)up1[r];
  }
}

// ---- kernel 2: out[N,512] = u8[N,256] @ Cw^T + C_b (fp32 out) ------------
// Block tile 128 rows x 64 out-cols; 4 K-iterations of 64.
// Counted-vmcnt A prefetch (As double-buffered, u8 is the big read here);
// Bs single-buffered (Cwb is L2-resident). LDS 40 KB -> 4 blocks/CU kept.
// Per-wave ledger at the wait in iter it (it<3):
//   outstanding = A(it):4 + B(it):2 + A(it+1):4 -> vmcnt(4) drains A(it),B(it).
// XCD swizzle: 8 cg blocks of a row tile share u8 rows -> same XCD L2.

__launch_bounds__(256, 4)
__global__ void k_out(const _Float16* __restrict__ u8,
                      const _Float16* __restrict__ Cwb,
                      const float* __restrict__ Cb,
                      float* __restrict__ out) {
  __shared__ __align__(16) uint16_t As[2][128 * 64];  // 2 x 16 KB u8 tile
  __shared__ __align__(16) uint16_t Bs[64 * 64];      //  8 KB Cw tile

  const int tid = threadIdx.x;
  const int wave = tid >> 6, lane = tid & 63;

  const int id = blockIdx.x;
  const int xcd = id & 7;
  const int s = id >> 3;                     // 0..511
  const int cg = s & 7;                      // 0..7 out-col group (64)
  const int rt = (xcd << 6) | (s >> 3);      // 0..511 row tile
  const int r0 = rt << 7;
  const int c0 = cg << 6;

  const int m_l = lane & 15, kq = lane >> 4;
  const int wrow = wave << 5;

  f32x4 acc[2][4];
#pragma unroll
  for (int a = 0; a < 2; a++)
#pragma unroll
    for (int b = 0; b < 4; b++)
      acc[a][b] = (f32x4){0.f, 0.f, 0.f, 0.f};

  const _Float16* aptr[4];
  const _Float16* bptr[2];
  int lofsA[4], lofsB[2];
#pragma unroll
  for (int j = 0; j < 4; j++) {
    int lin = (j << 8) + tid;
    int row = lin >> 3;
    int c = ((lin & 7) - row) & 7;
    lofsA[j] = lin << 4;
    aptr[j] = u8 + (size_t)(r0 + row) * KDIM + (c << 3);
  }
#pragma unroll
  for (int j = 0; j < 2; j++) {
    int lin = (j << 8) + tid;
    int row = lin >> 3;
    int c = ((lin & 7) - row) & 7;
    lofsB[j] = lin << 4;
    bptr[j] = Cwb + (size_t)(c0 + row) * KDIM + (c << 3);
  }

  // Prologue: issue A(0).
#pragma unroll
  for (int j = 0; j < 4; j++) gld_lds16(aptr[j], (char*)As[0] + lofsA[j]);
#pragma unroll
  for (int j = 0; j < 4; j++) aptr[j] += 64;

  for (int it = 0; it < KDIM / 64; it++) {
    const int cur = it & 1;
    __builtin_amdgcn_sched_barrier(0);
    __builtin_amdgcn_s_barrier();   // Bs & As[cur^1] free
    __builtin_amdgcn_sched_barrier(0);

#pragma unroll
    for (int j = 0; j < 2; j++) gld_lds16(bptr[j], (char*)Bs + lofsB[j]);
#pragma unroll
    for (int j = 0; j < 2; j++) bptr[j] += 64;

    if (it < KDIM / 64 - 1) {
#pragma unroll
      for (int j = 0; j < 4; j++)
        gld_lds16(aptr[j], (char*)As[cur ^ 1] + lofsA[j]);
#pragma unroll
      for (int j = 0; j < 4; j++) aptr[j] += 64;
      asm volatile("s_waitcnt vmcnt(4)" ::: "memory");  // A(it+1) stays in flight
    } else {
      asm volatile("s_waitcnt vmcnt(0)" ::: "memory");
    }
    __builtin_amdgcn_sched_barrier(0);
    __builtin_amdgcn_s_barrier();
    __builtin_amdgcn_sched_barrier(0);

#pragma unroll
    for (int ks = 0; ks < 2; ks++) {
      const int chunk = (ks << 2) + kq;
      f16x8 af[2];
#pragma unroll
      for (int mf = 0; mf < 2; mf++)
        af[mf] = *(const f16x8*)((char*)As[cur] + swz(wrow + (mf << 4) + m_l, chunk));
#pragma unroll
      for (int kf = 0; kf < 4; kf++) {
        f16x8 bv = *(const f16x8*)((char*)Bs + swz((kf << 4) + m_l, chunk));
#pragma unroll
        for (int mf = 0; mf < 2; mf++)
          acc[mf][kf] = __builtin_amdgcn_mfma_f32_16x16x32_f16(
              af[mf], bv, acc[mf][kf], 0, 0, 0);
      }
    }
  }

#pragma unroll
  for (int kf = 0; kf < 4; kf++) {
    const int col = c0 + (kf << 4) + m_l;
    const float cb = Cb[col];
#pragma unroll
    for (int mf = 0; mf < 2; mf++) {
      const int rbase = r0 + wrow + (mf << 4) + (kq << 2);
#pragma unroll
      for (int r = 0; r < 4; r++)
        out[(size_t)(rbase + r) * ODIM + col] = acc[mf][kf][r] + cb;
    }
  }
}

// ---- launch --------------------------------------------------------------

extern "C" void kernel_launch(void* const* d_in, const int* in_sizes, int n_in,
                              void* d_out, int out_size, void* d_ws, size_t ws_size,
                              hipStream_t stream) {
  const float* z  = (const float*)d_in[0];
  const float* T0 = (const float*)d_in[1];
  const float* T  = (const float*)d_in[2];
  const float* Cw = (const float*)d_in[3];
  const float* Cb = (const float*)d_in[4];
  float* out = (float*)d_out;

  // ws layout: z16 64MB | Tb 2MB | Cwb 256KB | u8 32MB  (total ~98.25 MB)
  char* ws = (char*)d_ws;
  _Float16* z16 = (_Float16*)ws;
  _Float16* Tb  = (_Float16*)(ws + (size_t)ZN * 2);
  _Float16* Cwb = (_Float16*)(ws + (size_t)ZN * 2 + (size_t)TN * 2);
  _Float16* u8  = (_Float16*)(ws + (size_t)ZN * 2 + (size_t)TN * 2 + (size_t)CWN * 2);

  // (ZN+TN+CWN)/4 threads / 256 = 33920 blocks exactly
  k_convert<<<33920, 256, 0, stream>>>(z, T, Cw, z16, Tb, Cwb);
  k_poly<<<8192, 256, 0, stream>>>(z16, T0, Tb, u8);
  k_out<<<4096, 256, 0, stream>>>(u8, Cwb, Cb, out);
}